// Round 1
// baseline (181.834 us; speedup 1.0000x reference)
//
#include <hip/hip_runtime.h>
#include <hip/hip_cooperative_groups.h>

// MMD loss, N=4096 per side, D=256, fp32.
// R17: residue attack #2. Total was 108 us with k_pairs only 44.9 -> ~63 us
//      lives in k_conv + 1-block k_scale + 2 dispatch boundaries. Work there
//      is ~10 us (conv 12 MB, scale 256 KB) -> boundary/serialization cost.
//      Fuse into ONE cooperative dispatch of 512 blocks (=2 blocks/CU
//      co-residency k_pairs already achieves):
//        A : conv, 16 rows/block over all 512 blocks; block0 zeroes atomic
//            accumulators (ws poisoned 0xAA -> must be written every launch).
//        -- grid.sync(): agent acq/rel replaces the kernel-boundary flush
//            that made the bf16-plane handoff legal (NO __threadfence: R8-R10).
//        A2: colsum/S1 partials (carried in REGISTERS across the sync)
//            atomicAdd'ed into 8 spread copies; counter bump made data-
//            dependent on the atomic RETURN VALUES so it cannot overtake.
//        B : frozen R15 k_pairs body in a grid-stride tile loop; scale is
//            computed per block AFTER the first tile's MFMA loop (counter
//            poll + 8-copy reduce hides under MFMA latency); one out-atomic
//            per block at the end.
//      k_pairs inner loop/epilogue math byte-identical to R16 (FROZEN).
//      Fallback: if hipLaunchCooperativeKernel errors cleanly, launch the
//      proven R16 3-kernel path (verbatim below).

#define NROWS 8192
#define HALF  4096
#define DIM   256
#define CONVB 256         // fallback k_conv blocks
#define NTILE 1056        // 256x128 tiles: sum_{I=0..31}(64-2I)
#define GRID  512         // cooperative grid: 2 blocks/CU x 256 CU

typedef __bf16 bf16x8 __attribute__((ext_vector_type(8)));
typedef float f32x4 __attribute__((ext_vector_type(4)));
typedef unsigned short ushort8 __attribute__((ext_vector_type(8)));

__device__ __forceinline__ const float* row_ptr(const float* src, const float* tgt, int r) {
    return (r < HALF) ? (src + (size_t)r * DIM) : (tgt + (size_t)(r - HALF) * DIM);
}

__device__ __forceinline__ unsigned short bf16_rne(float x) {
    unsigned int u = __builtin_bit_cast(unsigned int, x);
    return (unsigned short)((u + 0x7FFFu + ((u >> 16) & 1u)) >> 16);
}

// ===================== R17: single fused cooperative kernel =====================
__global__ __launch_bounds__(256, 2) void k_fused(
        const float* __restrict__ src, const float* __restrict__ tgt,
        unsigned short* __restrict__ hi, float* __restrict__ sq,
        float* __restrict__ colsumP,        // [8][DIM] spread atomic copies
        double* __restrict__ s1dP,          // [8]
        unsigned int* __restrict__ cnt,     // completion counter
        float* __restrict__ out) {
    __shared__ __align__(16) unsigned short sh_hi[16 * 32 * 8];  // 8 KB
    __shared__ float4 cs[4][64];
    __shared__ double s1s[4];
    __shared__ float wsum[4];

    int t = threadIdx.x, w = t >> 6, lane = t & 63;

    // ---------- Phase A: fp32 -> bf16 tiled plane, 16 rows/block ----------
    int r0 = blockIdx.x * 16;
    int g = lane >> 1, jj = lane & 1;

    float4 v[4];
    #pragma unroll
    for (int i = 0; i < 4; ++i)
        v[i] = ((const float4*)row_ptr(src, tgt, r0 + w * 4 + i))[lane];  // coalesced

    if (blockIdx.x == 0) {   // zero the poisoned atomic accumulators (pre-sync)
        #pragma unroll
        for (int k = 0; k < 8; ++k) colsumP[k * DIM + t] = 0.0f;
        if (t < 8) s1dP[t] = 0.0;
        if (t == 0) { *cnt = 0u; out[0] = 0.0f; }
    }

    float4 csum = {0.f, 0.f, 0.f, 0.f};
    double s1w = 0.0;
    #pragma unroll
    for (int i = 0; i < 4; ++i) {
        int rl = w * 4 + i;                          // local row 0..15
        float xs[4] = {v[i].x, v[i].y, v[i].z, v[i].w};
        unsigned short hs[4];
        #pragma unroll
        for (int k = 0; k < 4; ++k) hs[k] = bf16_rne(xs[k]);
        ushort4 h4 = {hs[0], hs[1], hs[2], hs[3]};
        *(ushort4*)&sh_hi[(g * 16 + rl) * 8 + jj * 4] = h4;
        csum.x += xs[0]; csum.y += xs[1]; csum.z += xs[2]; csum.w += xs[3];
        float s = xs[0]*xs[0] + xs[1]*xs[1] + xs[2]*xs[2] + xs[3]*xs[3];
        #pragma unroll
        for (int off = 32; off; off >>= 1) s += __shfl_xor(s, off, 64);
        if (lane == 0) { sq[r0 + rl] = s; s1w += (double)s; }
    }
    __syncthreads();
    // Coalesced tiled write-out: 512 chunks of 16 B (layout identical to R16).
    {
        int panel = r0 >> 7, rowbase = r0 & 127;
        #pragma unroll
        for (int c = t; c < 512; c += 256) {
            int gg = c >> 4, r = c & 15;
            size_t goff = (((size_t)panel * 32 + gg) * 128 + rowbase + r) * 8;
            *(ushort8*)&hi[goff] = *(const ushort8*)&sh_hi[(gg * 16 + r) * 8];
        }
    }
    cs[w][lane] = csum;
    if (lane == 0) s1s[w] = s1w;
    __syncthreads();
    float4 tot = {0.f, 0.f, 0.f, 0.f};
    double s1blk = 0.0;
    if (w == 0) {
        float4 a = cs[0][lane], b = cs[1][lane], c2 = cs[2][lane], d = cs[3][lane];
        tot.x = a.x + b.x + c2.x + d.x; tot.y = a.y + b.y + c2.y + d.y;
        tot.z = a.z + b.z + c2.z + d.z; tot.w = a.w + b.w + c2.w + d.w;
        s1blk = s1s[0] + s1s[1] + s1s[2] + s1s[3];
    }

    // ---------- grid-wide sync: publishes plane/sq/zeros to all XCDs ----------
    cooperative_groups::this_grid().sync();

    // ---------- Phase A2: cross-block reduction via device atomics ----------
    if (w == 0) {
        float* cp = colsumP + (blockIdx.x & 7) * DIM + lane * 4;
        float d0 = atomicAdd(cp + 0, tot.x);
        float d1 = atomicAdd(cp + 1, tot.y);
        float d2 = atomicAdd(cp + 2, tot.z);
        float d3 = atomicAdd(cp + 3, tot.w);
        float dep = (d0 + d1) + (d2 + d3);
        if (lane == 0) dep += (float)atomicAdd(&s1dP[blockIdx.x & 7], s1blk);
        // Returned atomics are globally committed; forcing the returns to be
        // consumed orders the counter bump after them (no __threadfence).
        asm volatile("" :: "v"(dep) : "memory");
        if (lane == 0) atomicAdd(cnt, 1u);
    }

    // ---------- Phase B: frozen R15 pairs body, grid-stride tile loop ----------
    int lr = lane & 15, lq = lane >> 4;
    float scale_f = 0.0f, wtot = 0.0f;
    bool have = false;

    for (int tile = blockIdx.x; tile < NTILE; tile += GRID) {
        int id = tile, I = 0;
        for (;;) { int cnt2 = 64 - 2 * I; if (id < cnt2) break; id -= cnt2; ++I; }
        int J  = 2 * I + id;
        int Pw = 2 * I + (w >> 1);                   // this wave's 128-row panel
        int hh = w & 1;                              // 64-row half within panel

        float wgt = (J == Pw) ? 1.0f : (J > Pw) ? 2.0f : 0.0f;
        float sgn = ((Pw < 32) == (J < 32)) ? 1.0f : -1.0f;

        size_t aBase = (size_t)Pw * 4096 + lq * 128 + hh * 64 + lr;
        size_t bBase = (size_t)J  * 4096 + lq * 128 + lr;
        const ushort8* pAh = (const ushort8*)hi + aBase;
        const ushort8* pBh = (const ushort8*)hi + bBase;

        f32x4 acc[4][8];
        #pragma unroll
        for (int m = 0; m < 4; ++m)
            #pragma unroll
            for (int n = 0; n < 8; ++n) acc[m][n] = (f32x4){0.f, 0.f, 0.f, 0.f};

        #pragma unroll
        for (int it = 0; it < DIM / 32; ++it) {
            bf16x8 aH[4], bH[8];
            #pragma unroll
            for (int m = 0; m < 4; ++m)
                aH[m] = __builtin_bit_cast(bf16x8, pAh[it * 512 + m * 16]);
            #pragma unroll
            for (int n = 0; n < 8; ++n)
                bH[n] = __builtin_bit_cast(bf16x8, pBh[it * 512 + n * 16]);
            #pragma unroll
            for (int m = 0; m < 4; ++m)
                #pragma unroll
                for (int n = 0; n < 8; ++n)
                    acc[m][n] = __builtin_amdgcn_mfma_f32_16x16x32_bf16(aH[m], bH[n], acc[m][n], 0, 0, 0);
        }

        // scale: computed once per block, hidden under the first tile's MFMA
        if (!have) {
            while (atomicAdd(cnt, 0u) < (unsigned)GRID) __builtin_amdgcn_s_sleep(2);
            float4 c4 = {0.f, 0.f, 0.f, 0.f};
            #pragma unroll
            for (int k = 0; k < 8; ++k) {
                float4 vv = *(const float4*)&colsumP[k * DIM + lane * 4];
                c4.x += vv.x; c4.y += vv.y; c4.z += vv.z; c4.w += vv.w;
            }
            double s2 = (double)c4.x * c4.x + (double)c4.y * c4.y
                      + (double)c4.z * c4.z + (double)c4.w * c4.w;
            #pragma unroll
            for (int off = 32; off; off >>= 1) s2 += __shfl_xor(s2, off, 64);
            double S1 = 0.0;
            #pragma unroll
            for (int k = 0; k < 8; ++k) S1 += s1dP[k];
            double nd    = (double)NROWS;
            double sumL2 = 2.0 * nd * S1 - 2.0 * s2;
            double bw    = sumL2 / (nd * nd - nd) / 4.0;   // / KERNEL_MUL^(KERNEL_NUM//2)
            scale_f = (float)(-1.0 / (16.0 * bw * 0.69314718055994530942));
            have = true;
        }

        // ---- epilogue: L2 -> sum of 5 Gaussian kernels -> reduce (frozen) ----
        int ro_eff = Pw * 128 + hh * 64;
        int co_eff = J * 128;
        float4 sqa4[4];
        float  sqbv[8];
        #pragma unroll
        for (int m = 0; m < 4; ++m) sqa4[m] = *(const float4*)&sq[ro_eff + m * 16 + lq * 4];
        #pragma unroll
        for (int n = 0; n < 8; ++n) sqbv[n] = sq[co_eff + n * 16 + lr];

        float tsum = 0.0f;
        #pragma unroll
        for (int m = 0; m < 4; ++m) {
            float sa[4] = {sqa4[m].x, sqa4[m].y, sqa4[m].z, sqa4[m].w};
            #pragma unroll
            for (int n = 0; n < 8; ++n) {
                #pragma unroll
                for (int r = 0; r < 4; ++r) {
                    float L2  = sa[r] + sqbv[n] - 2.0f * acc[m][n][r];
                    float u   = __builtin_amdgcn_exp2f(scale_f * L2);
                    float u2  = u * u;
                    float u4  = u2 * u2;
                    float u8  = u4 * u4;
                    float u16 = u8 * u8;
                    tsum += u + u2 + u4 + u8 + u16;
                }
            }
        }
        #pragma unroll
        for (int off = 32; off; off >>= 1) tsum += __shfl_xor(tsum, off, 64);
        wtot += tsum * sgn * wgt;                    // weighted running sum
    }

    if (lane == 0) wsum[w] = wtot;
    __syncthreads();
    if (t == 0) {
        float tot4 = wsum[0] + wsum[1] + wsum[2] + wsum[3];
        atomicAdd(out, tot4 * (1.0f / ((float)HALF * (float)HALF)));
    }
}

// ===================== R16 fallback path (verbatim, proven 108 us) =====================
__global__ __launch_bounds__(256) void k_conv(const float* __restrict__ src,
                                              const float* __restrict__ tgt,
                                              unsigned short* __restrict__ hi,
                                              float* __restrict__ sq,
                                              float* __restrict__ part,
                                              double* __restrict__ parts1,
                                              float* __restrict__ out) {
    __shared__ __align__(16) unsigned short sh_hi[32 * 32 * 8];  // 16 KB
    __shared__ float4 cs[4][64];
    __shared__ double s1s[4];

    int w = threadIdx.x >> 6, lane = threadIdx.x & 63;
    int r0 = blockIdx.x * 32;
    int g  = lane >> 1, j = lane & 1;

    float4 v[8];
    #pragma unroll
    for (int i = 0; i < 8; ++i) {
        int row = r0 + w * 8 + i;
        v[i] = ((const float4*)row_ptr(src, tgt, row))[lane];
    }

    float4 csum = {0.f, 0.f, 0.f, 0.f};
    double s1w = 0.0;
    #pragma unroll
    for (int i = 0; i < 8; ++i) {
        int rl  = w * 8 + i;
        float xs[4] = {v[i].x, v[i].y, v[i].z, v[i].w};
        unsigned short hs[4];
        #pragma unroll
        for (int k = 0; k < 4; ++k) hs[k] = bf16_rne(xs[k]);
        ushort4 h4 = {hs[0], hs[1], hs[2], hs[3]};
        int so = (g * 32 + rl) * 8 + j * 4;
        *(ushort4*)&sh_hi[so] = h4;
        csum.x += xs[0]; csum.y += xs[1]; csum.z += xs[2]; csum.w += xs[3];
        float s = xs[0] * xs[0] + xs[1] * xs[1] + xs[2] * xs[2] + xs[3] * xs[3];
        #pragma unroll
        for (int off = 32; off; off >>= 1) s += __shfl_xor(s, off, 64);
        if (lane == 0) { sq[r0 + rl] = s; s1w += (double)s; }
    }
    __syncthreads();
    int panel = blockIdx.x >> 2, quarter = blockIdx.x & 3;
    #pragma unroll
    for (int c = threadIdx.x; c < 1024; c += 256) {
        int gg = c >> 5, r = c & 31;
        size_t goff = (((size_t)panel * 32 + gg) * 128 + quarter * 32 + r) * 8;
        *(ushort8*)&hi[goff] = *(const ushort8*)&sh_hi[c * 8];
    }
    cs[w][lane] = csum;
    if (lane == 0) s1s[w] = s1w;
    __syncthreads();
    if (w == 0) {
        float4 a = cs[0][lane], b = cs[1][lane], c = cs[2][lane], d = cs[3][lane];
        float4 tot = {a.x + b.x + c.x + d.x, a.y + b.y + c.y + d.y,
                      a.z + b.z + c.z + d.z, a.w + b.w + c.w + d.w};
        *(float4*)&part[(size_t)blockIdx.x * DIM + lane * 4] = tot;
        if (lane == 0) parts1[blockIdx.x] = s1s[0] + s1s[1] + s1s[2] + s1s[3];
    }
    if (blockIdx.x == 0 && threadIdx.x == 0) out[0] = 0.0f;
}

__global__ __launch_bounds__(256) void k_scale(const double* __restrict__ parts1,
                                               const float* __restrict__ part,
                                               float* __restrict__ scale) {
    __shared__ double sh[256];
    int t = threadIdx.x;
    sh[t] = parts1[t];
    __syncthreads();
    for (int off = 128; off; off >>= 1) {
        if (t < off) sh[t] += sh[t + off];
        __syncthreads();
    }
    double S1 = sh[0];
    __syncthreads();
    float c0 = 0.f, c1 = 0.f, c2 = 0.f, c3 = 0.f;
    #pragma unroll 16
    for (int b = 0; b < CONVB; b += 4) {
        c0 += part[(b + 0) * DIM + t];
        c1 += part[(b + 1) * DIM + t];
        c2 += part[(b + 2) * DIM + t];
        c3 += part[(b + 3) * DIM + t];
    }
    double c = (double)((c0 + c1) + (c2 + c3));
    sh[t] = c * c;
    __syncthreads();
    for (int off = 128; off; off >>= 1) {
        if (t < off) sh[t] += sh[t + off];
        __syncthreads();
    }
    if (t == 0) {
        double S2    = sh[0];
        double n     = (double)NROWS;
        double sumL2 = 2.0 * n * S1 - 2.0 * S2;
        double bw    = sumL2 / (n * n - n) / 4.0;
        *scale = (float)(-1.0 / (16.0 * bw * 0.69314718055994530942));
    }
}

__global__ __launch_bounds__(256, 2) void k_pairs(const unsigned short* __restrict__ hi,
                                                  const float* __restrict__ sq,
                                                  const float* __restrict__ scale_p,
                                                  float* __restrict__ out) {
    int id = blockIdx.x;
    int I = 0;
    for (;;) {
        int cnt = 64 - 2 * I;
        if (id < cnt) break;
        id -= cnt; ++I;
    }
    int J = 2 * I + id;

    __shared__ float wsum[4];

    int t    = threadIdx.x;
    int lane = t & 63;
    int w    = t >> 6;
    int lr   = lane & 15, lq = lane >> 4;
    int Pw   = 2 * I + (w >> 1);
    int hh   = w & 1;

    float wgt = (J == Pw) ? 1.0f : (J > Pw) ? 2.0f : 0.0f;
    float sgn = ((Pw < 32) == (J < 32)) ? 1.0f : -1.0f;

    size_t aBase = (size_t)Pw * 4096 + lq * 128 + hh * 64 + lr;
    size_t bBase = (size_t)J  * 4096 + lq * 128 + lr;
    const ushort8* pAh = (const ushort8*)hi + aBase;
    const ushort8* pBh = (const ushort8*)hi + bBase;

    f32x4 acc[4][8];
    #pragma unroll
    for (int m = 0; m < 4; ++m)
        #pragma unroll
        for (int n = 0; n < 8; ++n) acc[m][n] = (f32x4){0.f, 0.f, 0.f, 0.f};

    #pragma unroll
    for (int it = 0; it < DIM / 32; ++it) {
        bf16x8 aH[4], bH[8];
        #pragma unroll
        for (int m = 0; m < 4; ++m)
            aH[m] = __builtin_bit_cast(bf16x8, pAh[it * 512 + m * 16]);
        #pragma unroll
        for (int n = 0; n < 8; ++n)
            bH[n] = __builtin_bit_cast(bf16x8, pBh[it * 512 + n * 16]);
        #pragma unroll
        for (int m = 0; m < 4; ++m)
            #pragma unroll
            for (int n = 0; n < 8; ++n)
                acc[m][n] = __builtin_amdgcn_mfma_f32_16x16x32_bf16(aH[m], bH[n], acc[m][n], 0, 0, 0);
    }

    float scale = *scale_p;
    int ro_eff = Pw * 128 + hh * 64;
    int co_eff = J * 128;
    float4 sqa4[4];
    float  sqbv[8];
    #pragma unroll
    for (int m = 0; m < 4; ++m) sqa4[m] = *(const float4*)&sq[ro_eff + m * 16 + lq * 4];
    #pragma unroll
    for (int n = 0; n < 8; ++n) sqbv[n] = sq[co_eff + n * 16 + lr];

    float tsum = 0.0f;
    #pragma unroll
    for (int m = 0; m < 4; ++m) {
        float sa[4] = {sqa4[m].x, sqa4[m].y, sqa4[m].z, sqa4[m].w};
        #pragma unroll
        for (int n = 0; n < 8; ++n) {
            #pragma unroll
            for (int r = 0; r < 4; ++r) {
                float L2  = sa[r] + sqbv[n] - 2.0f * acc[m][n][r];
                float u   = __builtin_amdgcn_exp2f(scale * L2);
                float u2  = u * u;
                float u4  = u2 * u2;
                float u8  = u4 * u4;
                float u16 = u8 * u8;
                tsum += u + u2 + u4 + u8 + u16;
            }
        }
    }

    #pragma unroll
    for (int off = 32; off; off >>= 1) tsum += __shfl_xor(tsum, off, 64);
    if (lane == 0) wsum[w] = tsum * sgn * wgt;
    __syncthreads();
    if (t == 0) {
        float tot = wsum[0] + wsum[1] + wsum[2] + wsum[3];
        atomicAdd(out, tot * (1.0f / ((float)HALF * (float)HALF)));
    }
}

extern "C" void kernel_launch(void* const* d_in, const int* in_sizes, int n_in,
                              void* d_out, int out_size, void* d_ws, size_t ws_size,
                              hipStream_t stream) {
    const float* src = (const float*)d_in[0];
    const float* tgt = (const float*)d_in[1];
    float* out = (float*)d_out;
    char* ws = (char*)d_ws;

    // R17 fused layout (disjoint use from fallback layout; only one path runs)
    unsigned int* cnt   = (unsigned int*)(ws + 0);        // 4 B
    double* s1dP        = (double*)(ws + 64);             // 64 B
    float*  colsumP     = (float*)(ws + 128);             // 8 KB
    float*  sqF         = (float*)(ws + 8448);            // 32 KB
    unsigned short* hiF = (unsigned short*)(ws + 65536);  // 4 MB, 16B-aligned

    void* args[8];
    args[0] = (void*)&src;  args[1] = (void*)&tgt;
    args[2] = (void*)&hiF;  args[3] = (void*)&sqF;
    args[4] = (void*)&colsumP; args[5] = (void*)&s1dP;
    args[6] = (void*)&cnt;  args[7] = (void*)&out;

    hipError_t e = hipLaunchCooperativeKernel((const void*)k_fused, dim3(GRID),
                                              dim3(256), args, 0, stream);
    if (e != hipSuccess) {
        // Fallback: proven R16 3-kernel path with its original ws layout.
        float*  scale  = (float*)(ws + 16);
        float*  sq     = (float*)(ws + 64);
        float*  part   = (float*)(ws + 64 + 32768);
        double* parts1 = (double*)(ws + 64 + 32768 + 262144);
        unsigned short* hi = (unsigned short*)(ws + 297024);
        k_conv <<<CONVB, 256, 0, stream>>>(src, tgt, hi, sq, part, parts1, out);
        k_scale<<<1, 256, 0, stream>>>(parts1, part, scale);
        k_pairs<<<NTILE, 256, 0, stream>>>(hi, sq, scale, out);
    }
}

// Round 2
// 110.969 us; speedup vs baseline: 1.6386x; 1.6386x over previous
//
#include <hip/hip_runtime.h>

// MMD loss, N=4096 per side, D=256, fp32.
// R18: revert R17 fusion (cooperative path cost +74 us total: grid-stride
//      tail, contended cnt-spin, grid.sync flush; AND proved the ~63 us
//      total-vs-kernel residue is FIXED harness overhead -- single-dispatch
//      R17 still showed a 69 us residue). k_conv/k_scale are therefore
//      near-free: kept byte-identical to R16. The only lever is k_pairs
//      (44.9 us vs ~7 us MFMA floor, every pipe <30% busy = latency-bound).
//      R16's frozen k_pairs had 116 arch + 128 acc = 244/256 VGPRs -> ~12
//      free regs -> compiler CANNOT pipeline the 12-load burst vs MFMAs;
//      each k-iter eats a full L2 latency. R18 k_pairs:
//        - 128x128 tile, triangular J>=I cover (2080 blocks, zero wasted
//          waves, 4.06 rounds -> smoother tail), wave tile 64x64.
//        - acc[4][4] (64 regs) + explicit 1-deep double-buffered fragment
//          prefetch (8 loads of iter i+1 issued before iter i's 16 MFMAs).
//          ~190 regs total: keeps 2 blocks/CU AND ~65 regs scheduler slack.
//        - no barriers anywhere -> compiler free to use counted vmcnt.
//      Epilogue math / bf16 plane layout / atomics unchanged (R13-verified
//      jitter tolerance; sum order change only).
//      Lessons enforced: NO __threadfence (R8-R10), NO cooperative launch
//      (R17), frag/acc arrays indexed only by fully-unrolled vars (R8/R9),
//      single-pass bf16 (R10+), tiled plane (R6).

#define NROWS 8192
#define HALF  4096
#define DIM   256
#define CONVB 256         // k_conv blocks; 32 rows each (quarter panel)
#define NTILE 2080        // 128x128 tiles: 64*65/2, J>=I

typedef __bf16 bf16x8 __attribute__((ext_vector_type(8)));
typedef float f32x4 __attribute__((ext_vector_type(4)));
typedef unsigned short ushort8 __attribute__((ext_vector_type(8)));

__device__ __forceinline__ const float* row_ptr(const float* src, const float* tgt, int r) {
    return (r < HALF) ? (src + (size_t)r * DIM) : (tgt + (size_t)(r - HALF) * DIM);
}

__device__ __forceinline__ unsigned short bf16_rne(float x) {
    unsigned int u = __builtin_bit_cast(unsigned int, x);
    return (unsigned short)((u + 0x7FFFu + ((u >> 16) & 1u)) >> 16);
}

// --- Phase 0: fp32 -> bf16 plane (tiled) + sq[] + colsum/S1 partials ---
// Tiled plane layout: 16B-granule index of (global row R, k-granule g) =
//   (R>>7)*4096 + g*128 + (R&127)        [panel-major, granule-major inside]
__global__ __launch_bounds__(256) void k_conv(const float* __restrict__ src,
                                              const float* __restrict__ tgt,
                                              unsigned short* __restrict__ hi,
                                              float* __restrict__ sq,
                                              float* __restrict__ part,
                                              double* __restrict__ parts1,
                                              float* __restrict__ out) {
    __shared__ __align__(16) unsigned short sh_hi[32 * 32 * 8];  // 16 KB
    __shared__ float4 cs[4][64];
    __shared__ double s1s[4];

    int w = threadIdx.x >> 6, lane = threadIdx.x & 63;
    int r0 = blockIdx.x * 32;                       // 32 rows per block
    int g  = lane >> 1, j = lane & 1;               // lane's float4 = half-granule

    // All 8 row-loads issued up front: 8 outstanding HBM loads per thread.
    float4 v[8];
    #pragma unroll
    for (int i = 0; i < 8; ++i) {
        int row = r0 + w * 8 + i;
        v[i] = ((const float4*)row_ptr(src, tgt, row))[lane];   // coalesced
    }

    float4 csum = {0.f, 0.f, 0.f, 0.f};
    double s1w = 0.0;
    #pragma unroll
    for (int i = 0; i < 8; ++i) {
        int rl  = w * 8 + i;                        // local row 0..31
        float xs[4] = {v[i].x, v[i].y, v[i].z, v[i].w};
        unsigned short hs[4];
        #pragma unroll
        for (int k = 0; k < 4; ++k) hs[k] = bf16_rne(xs[k]);
        ushort4 h4 = {hs[0], hs[1], hs[2], hs[3]};
        int so = (g * 32 + rl) * 8 + j * 4;
        *(ushort4*)&sh_hi[so] = h4;
        csum.x += xs[0]; csum.y += xs[1]; csum.z += xs[2]; csum.w += xs[3];
        float s = xs[0] * xs[0] + xs[1] * xs[1] + xs[2] * xs[2] + xs[3] * xs[3];
        #pragma unroll
        for (int off = 32; off; off >>= 1) s += __shfl_xor(s, off, 64);
        if (lane == 0) { sq[r0 + rl] = s; s1w += (double)s; }
    }
    __syncthreads();
    // Coalesced tiled write-out: 1024 chunks of 16 B.
    int panel = blockIdx.x >> 2, quarter = blockIdx.x & 3;
    #pragma unroll
    for (int c = threadIdx.x; c < 1024; c += 256) {
        int gg = c >> 5, r = c & 31;
        size_t goff = (((size_t)panel * 32 + gg) * 128 + quarter * 32 + r) * 8;
        *(ushort8*)&hi[goff] = *(const ushort8*)&sh_hi[c * 8];
    }
    // colsum + S1 partials (per-block slots, no contention)
    cs[w][lane] = csum;
    if (lane == 0) s1s[w] = s1w;
    __syncthreads();
    if (w == 0) {
        float4 a = cs[0][lane], b = cs[1][lane], c = cs[2][lane], d = cs[3][lane];
        float4 tot = {a.x + b.x + c.x + d.x, a.y + b.y + c.y + d.y,
                      a.z + b.z + c.z + d.z, a.w + b.w + c.w + d.w};
        *(float4*)&part[(size_t)blockIdx.x * DIM + lane * 4] = tot;
        if (lane == 0) parts1[blockIdx.x] = s1s[0] + s1s[1] + s1s[2] + s1s[3];
    }
    if (blockIdx.x == 0 && threadIdx.x == 0) out[0] = 0.0f;  // d_out was 0xAA
}

// --- Phase 1: bandwidth -> exp2 scale factor (pipelined reductions) ---
__global__ __launch_bounds__(256) void k_scale(const double* __restrict__ parts1,
                                               const float* __restrict__ part,
                                               float* __restrict__ scale) {
    __shared__ double sh[256];
    int t = threadIdx.x;
    sh[t] = parts1[t];
    __syncthreads();
    for (int off = 128; off; off >>= 1) {
        if (t < off) sh[t] += sh[t + off];
        __syncthreads();
    }
    double S1 = sh[0];
    __syncthreads();
    float c0 = 0.f, c1 = 0.f, c2 = 0.f, c3 = 0.f;
    #pragma unroll 16
    for (int b = 0; b < CONVB; b += 4) {
        c0 += part[(b + 0) * DIM + t];
        c1 += part[(b + 1) * DIM + t];
        c2 += part[(b + 2) * DIM + t];
        c3 += part[(b + 3) * DIM + t];
    }
    double c = (double)((c0 + c1) + (c2 + c3));
    sh[t] = c * c;
    __syncthreads();
    for (int off = 128; off; off >>= 1) {
        if (t < off) sh[t] += sh[t + off];
        __syncthreads();
    }
    if (t == 0) {
        double S2    = sh[0];
        double n     = (double)NROWS;
        double sumL2 = 2.0 * n * S1 - 2.0 * S2;
        double bw    = sumL2 / (n * n - n) / 4.0;   // / KERNEL_MUL^(KERNEL_NUM//2)
        // u = exp(-L2/(16*bw)) = exp2(scale * L2)
        *scale = (float)(-1.0 / (16.0 * bw * 0.69314718055994530942));
    }
}

// --- Phase 2: barrier-free bf16 MFMA pair kernel, 128x128 tile, J>=I ---
// Wave tile 64x64: acc[4][4] (64 VGPR) + double-buffered frags (64 VGPR)
// -> ~190/256 regs: 2 blocks/CU retained AND scheduler slack for counted
// vmcnt pipelining of the 8-load burst under the 16-MFMA cluster.
__global__ __launch_bounds__(256, 2) void k_pairs(const unsigned short* __restrict__ hi,
                                                  const float* __restrict__ sq,
                                                  const float* __restrict__ scale_p,
                                                  float* __restrict__ out) {
    // Triangular decode: row panel I (128 rows), col panel J = I..63.
    int id = blockIdx.x;
    int I = 0;
    for (;;) {
        int cnt = 64 - I;
        if (id < cnt) break;
        id -= cnt; ++I;
    }
    int J = I + id;

    __shared__ float wsum[4];

    int t    = threadIdx.x;
    int lane = t & 63;
    int w    = t >> 6;
    int lr   = lane & 15, lq = lane >> 4;
    int wr   = w >> 1, wc = w & 1;                  // 2x2 wave grid of 64x64

    // Block-uniform weight/sign: full diag tile counted once, off-diag x2.
    float wgt = (J == I) ? 1.0f : 2.0f;
    float sgn = ((I < 32) == (J < 32)) ? 1.0f : -1.0f;

    size_t aBase = (size_t)I * 4096 + (size_t)lq * 128 + wr * 64 + lr;
    size_t bBase = (size_t)J * 4096 + (size_t)lq * 128 + wc * 64 + lr;
    const ushort8* pAh = (const ushort8*)hi + aBase;
    const ushort8* pBh = (const ushort8*)hi + bBase;

    f32x4 acc[4][4];
    #pragma unroll
    for (int m = 0; m < 4; ++m)
        #pragma unroll
        for (int n = 0; n < 4; ++n) acc[m][n] = (f32x4){0.f, 0.f, 0.f, 0.f};

    // Explicit 1-deep double-buffered k-loop: iter i+1's 8 loads issued
    // BEFORE iter i's 16 MFMAs. Fully unrolled -> all indices static.
    bf16x8 aH[2][4], bH[2][4];
    #pragma unroll
    for (int m = 0; m < 4; ++m) aH[0][m] = __builtin_bit_cast(bf16x8, pAh[m * 16]);
    #pragma unroll
    for (int n = 0; n < 4; ++n) bH[0][n] = __builtin_bit_cast(bf16x8, pBh[n * 16]);

    #pragma unroll
    for (int it = 0; it < DIM / 32; ++it) {
        int cur = it & 1, nxt = cur ^ 1;
        if (it < DIM / 32 - 1) {
            #pragma unroll
            for (int m = 0; m < 4; ++m)
                aH[nxt][m] = __builtin_bit_cast(bf16x8, pAh[(it + 1) * 512 + m * 16]);
            #pragma unroll
            for (int n = 0; n < 4; ++n)
                bH[nxt][n] = __builtin_bit_cast(bf16x8, pBh[(it + 1) * 512 + n * 16]);
        }
        #pragma unroll
        for (int m = 0; m < 4; ++m)
            #pragma unroll
            for (int n = 0; n < 4; ++n)
                acc[m][n] = __builtin_amdgcn_mfma_f32_16x16x32_bf16(aH[cur][m], bH[cur][n], acc[m][n], 0, 0, 0);
    }

    // ---- epilogue: L2 -> sum of 5 Gaussian kernels -> reduce (frozen math)
    float scale = *scale_p;
    int ro_eff = I * 128 + wr * 64;
    int co_eff = J * 128 + wc * 64;
    float4 sqa4[4];
    float  sqbv[4];
    #pragma unroll
    for (int m = 0; m < 4; ++m) sqa4[m] = *(const float4*)&sq[ro_eff + m * 16 + lq * 4];
    #pragma unroll
    for (int n = 0; n < 4; ++n) sqbv[n] = sq[co_eff + n * 16 + lr];

    float tsum = 0.0f;
    #pragma unroll
    for (int m = 0; m < 4; ++m) {
        float sa[4] = {sqa4[m].x, sqa4[m].y, sqa4[m].z, sqa4[m].w};
        #pragma unroll
        for (int n = 0; n < 4; ++n) {
            #pragma unroll
            for (int r = 0; r < 4; ++r) {
                float L2  = sa[r] + sqbv[n] - 2.0f * acc[m][n][r];
                float u   = __builtin_amdgcn_exp2f(scale * L2);
                float u2  = u * u;
                float u4  = u2 * u2;
                float u8  = u4 * u4;
                float u16 = u8 * u8;
                tsum += u + u2 + u4 + u8 + u16;     // 5 kernel scales
            }
        }
    }

    #pragma unroll
    for (int off = 32; off; off >>= 1) tsum += __shfl_xor(tsum, off, 64);
    if (lane == 0) wsum[w] = tsum;
    __syncthreads();
    if (t == 0) {
        float tot = wsum[0] + wsum[1] + wsum[2] + wsum[3];
        // pre-normalized float atomic straight into d_out (R13-verified)
        atomicAdd(out, tot * sgn * wgt * (1.0f / ((float)HALF * (float)HALF)));
    }
}

extern "C" void kernel_launch(void* const* d_in, const int* in_sizes, int n_in,
                              void* d_out, int out_size, void* d_ws, size_t ws_size,
                              hipStream_t stream) {
    const float* src = (const float*)d_in[0];
    const float* tgt = (const float*)d_in[1];
    float* out = (float*)d_out;

    char* ws = (char*)d_ws;
    float*  scale  = (float*)(ws + 16);                          // 4 B
    float*  sq     = (float*)(ws + 64);                          // 32768 B
    float*  part   = (float*)(ws + 64 + 32768);                  // 256*256*4 B
    double* parts1 = (double*)(ws + 64 + 32768 + 262144);        // 256*8 B
    unsigned short* hi = (unsigned short*)(ws + 297024);         // 4 MB, 16B-aligned

    k_conv <<<CONVB, 256, 0, stream>>>(src, tgt, hi, sq, part, parts1, out);
    k_scale<<<1, 256, 0, stream>>>(parts1, part, scale);
    k_pairs<<<NTILE, 256, 0, stream>>>(hi, sq, scale, out);
}

// Round 3
// 104.588 us; speedup vs baseline: 1.7386x; 1.0610x over previous
//
#include <hip/hip_runtime.h>

// MMD loss, N=4096 per side, D=256, fp32.
// R19: fp8-e4m3 fragment plane. Evidence: R18 doubled occupancy (13->29.5%)
//      + explicit dbuf -> NO gain (49 us); L2-hot replay dispatch also 49 us
//      with ~zero HBM traffic -> binder is the per-CU VMEM pipe (fragment
//      load bytes + instruction count on the L2-hit path), not occupancy/
//      HBM/MFMA. Fix: halve BOTH. mfma_f32_16x16x32_fp8_fp8 = same rate as
//      bf16, operands 8B/lane. Plane packs each 16B unit as the lane's two
//      k-octets (k, k+32) -> one dwordx4 feeds TWO MFMA k-blocks, zero
//      waste: 32 loads/wave (was 64), 32KB (was 64KB), all issued upfront.
//      Accuracy: sq[] computed from the QUANTIZED vectors (|x_hat|^2, fp32
//      exact) -> diagonal L2 == 0 exactly, independent of cvt rounding;
//      S1/colsum stay fp32 so bandwidth matches reference. Cross-term
//      jitter ~8e-4 in exponent, random -> ~1e-6 final (thr 2.9e-5).
//      Geometry frozen from R18 (128x128 tile, J>=I, 64x64 wave, acc[4][4]).
//      Lessons enforced: NO __threadfence (R8-R10), NO cooperative launch
//      (R17), arrays indexed only by fully-unrolled vars (R8/R9), tiled
//      plane (R6), occupancy is not the lever (R18).

#define NROWS 8192
#define HALF  4096
#define DIM   256
#define CONVB 256         // k_conv blocks; 32 rows each (quarter panel)
#define NTILE 2080        // 128x128 tiles: 64*65/2, J>=I

typedef float f32x4 __attribute__((ext_vector_type(4)));

__device__ __forceinline__ const float* row_ptr(const float* src, const float* tgt, int r) {
    return (r < HALF) ? (src + (size_t)r * DIM) : (tgt + (size_t)(r - HALF) * DIM);
}

// --- Phase 0: fp32 -> fp8 plane (tiled, k-interleaved) + sq/colsum/S1 ---
// Plane unit = 16B of row R: unit u (0..15) = (t=u>>2, j=u&3) holds octets
//   bytes k[64t+8j .. +7]  (-> MFMA block 2t,  lane lq=j)
//   bytes k[64t+32+8j .. +7] (-> MFMA block 2t+1, lane lq=j)
// Unit index of (row R, u) = (R>>7)*2048 + u*128 + (R&127).
__global__ __launch_bounds__(256) void k_conv(const float* __restrict__ src,
                                              const float* __restrict__ tgt,
                                              unsigned char* __restrict__ hi,
                                              float* __restrict__ sq,
                                              float* __restrict__ part,
                                              double* __restrict__ parts1,
                                              float* __restrict__ out) {
    __shared__ __align__(16) unsigned char sh8[32 * 256];  // 8 KB, octet-swizzled
    __shared__ float4 cs[4][64];
    __shared__ double s1s[4];

    int w = threadIdx.x >> 6, lane = threadIdx.x & 63;
    int r0 = blockIdx.x * 32;                       // 32 rows per block

    // All 8 row-loads issued up front: 8 outstanding HBM loads per thread.
    float4 v[8];
    #pragma unroll
    for (int i = 0; i < 8; ++i) {
        int row = r0 + w * 8 + i;
        v[i] = ((const float4*)row_ptr(src, tgt, row))[lane];   // coalesced
    }

    float4 csum = {0.f, 0.f, 0.f, 0.f};
    double s1w = 0.0;
    #pragma unroll
    for (int i = 0; i < 8; ++i) {
        int rl  = w * 8 + i;                        // local row 0..31
        float xs[4] = {v[i].x, v[i].y, v[i].z, v[i].w};
        // pack 4 consecutive k into 4 fp8 bytes (HW cvt, OCP e4m3fn)
        int pk = __builtin_amdgcn_cvt_pk_fp8_f32(xs[0], xs[1], 0, false);
        pk     = __builtin_amdgcn_cvt_pk_fp8_f32(xs[2], xs[3], pk, true);
        int o  = lane >> 1, h = lane & 1;           // octet 0..31, 4B half
        // XOR-swizzled octet slot: store/read both use (oct ^ rl) & 31
        *(int*)&sh8[rl * 256 + (((o ^ rl) & 31) << 3) + (h << 2)] = pk;
        // colsum + S1 from FP32 (bandwidth must match reference exactly)
        csum.x += xs[0]; csum.y += xs[1]; csum.z += xs[2]; csum.w += xs[3];
        float sf = xs[0]*xs[0] + xs[1]*xs[1] + xs[2]*xs[2] + xs[3]*xs[3];
        // sq[] from QUANTIZED values -> diagonal L2 is exactly 0
        float q0 = __builtin_amdgcn_cvt_f32_fp8(pk, 0);
        float q1 = __builtin_amdgcn_cvt_f32_fp8(pk, 1);
        float q2 = __builtin_amdgcn_cvt_f32_fp8(pk, 2);
        float q3 = __builtin_amdgcn_cvt_f32_fp8(pk, 3);
        float sQ = q0*q0 + q1*q1 + q2*q2 + q3*q3;
        #pragma unroll
        for (int off = 32; off; off >>= 1) {
            sf += __shfl_xor(sf, off, 64);
            sQ += __shfl_xor(sQ, off, 64);
        }
        if (lane == 0) { sq[r0 + rl] = sQ; s1w += (double)sf; }
    }
    __syncthreads();
    // Coalesced tiled write-out: 512 units of 16 B (k-interleaved pairing).
    int panel = blockIdx.x >> 2, quarter = blockIdx.x & 3;
    #pragma unroll
    for (int c = threadIdx.x; c < 512; c += 256) {
        int u = c >> 5, rl = c & 31;
        int tt = u >> 2, j = u & 3;
        int o0 = 8 * tt + j;                        // k[64t+8j]
        int o1 = 8 * tt + 4 + j;                    // k[64t+32+8j]
        unsigned long long q0 = *(const unsigned long long*)
            &sh8[rl * 256 + (((o0 ^ rl) & 31) << 3)];
        unsigned long long q1 = *(const unsigned long long*)
            &sh8[rl * 256 + (((o1 ^ rl) & 31) << 3)];
        ulonglong2 q = {q0, q1};
        size_t goff = ((size_t)panel * 2048 + (size_t)u * 128 + quarter * 32 + rl);
        ((ulonglong2*)hi)[goff] = q;
    }
    // colsum + S1 partials (per-block slots, no contention)
    cs[w][lane] = csum;
    if (lane == 0) s1s[w] = s1w;
    __syncthreads();
    if (w == 0) {
        float4 a = cs[0][lane], b = cs[1][lane], c = cs[2][lane], d = cs[3][lane];
        float4 tot = {a.x + b.x + c.x + d.x, a.y + b.y + c.y + d.y,
                      a.z + b.z + c.z + d.z, a.w + b.w + c.w + d.w};
        *(float4*)&part[(size_t)blockIdx.x * DIM + lane * 4] = tot;
        if (lane == 0) parts1[blockIdx.x] = s1s[0] + s1s[1] + s1s[2] + s1s[3];
    }
    if (blockIdx.x == 0 && threadIdx.x == 0) out[0] = 0.0f;  // d_out was 0xAA
}

// --- Phase 1: bandwidth -> exp2 scale factor (unchanged, fp32 stats) ---
__global__ __launch_bounds__(256) void k_scale(const double* __restrict__ parts1,
                                               const float* __restrict__ part,
                                               float* __restrict__ scale) {
    __shared__ double sh[256];
    int t = threadIdx.x;
    sh[t] = parts1[t];
    __syncthreads();
    for (int off = 128; off; off >>= 1) {
        if (t < off) sh[t] += sh[t + off];
        __syncthreads();
    }
    double S1 = sh[0];
    __syncthreads();
    float c0 = 0.f, c1 = 0.f, c2 = 0.f, c3 = 0.f;
    #pragma unroll 16
    for (int b = 0; b < CONVB; b += 4) {
        c0 += part[(b + 0) * DIM + t];
        c1 += part[(b + 1) * DIM + t];
        c2 += part[(b + 2) * DIM + t];
        c3 += part[(b + 3) * DIM + t];
    }
    double c = (double)((c0 + c1) + (c2 + c3));
    sh[t] = c * c;
    __syncthreads();
    for (int off = 128; off; off >>= 1) {
        if (t < off) sh[t] += sh[t + off];
        __syncthreads();
    }
    if (t == 0) {
        double S2    = sh[0];
        double n     = (double)NROWS;
        double sumL2 = 2.0 * n * S1 - 2.0 * S2;
        double bw    = sumL2 / (n * n - n) / 4.0;   // / KERNEL_MUL^(KERNEL_NUM//2)
        // u = exp(-L2/(16*bw)) = exp2(scale * L2)
        *scale = (float)(-1.0 / (16.0 * bw * 0.69314718055994530942));
    }
}

// --- Phase 2: barrier-free fp8 MFMA pair kernel, 128x128 tile, J>=I ---
// 32 dwordx4 fragment loads per wave issued upfront (max MLP); each 16B
// feeds TWO mfma_f32_16x16x32_fp8_fp8 k-blocks (octets .x / .y).
__global__ __launch_bounds__(256, 2) void k_pairs(const unsigned char* __restrict__ hi,
                                                  const float* __restrict__ sq,
                                                  const float* __restrict__ scale_p,
                                                  float* __restrict__ out) {
    // Triangular decode: row panel I (128 rows), col panel J = I..63.
    int id = blockIdx.x;
    int I = 0;
    for (;;) {
        int cnt = 64 - I;
        if (id < cnt) break;
        id -= cnt; ++I;
    }
    int J = I + id;

    __shared__ float wsum[4];

    int t    = threadIdx.x;
    int lane = t & 63;
    int w    = t >> 6;
    int lr   = lane & 15, lq = lane >> 4;
    int wr   = w >> 1, wc = w & 1;                  // 2x2 wave grid of 64x64

    float wgt = (J == I) ? 1.0f : 2.0f;
    float sgn = ((I < 32) == (J < 32)) ? 1.0f : -1.0f;

    const ulonglong2* hp = (const ulonglong2*)hi;
    const ulonglong2* pA = hp + (size_t)I * 2048 + (size_t)lq * 128 + wr * 64 + lr;
    const ulonglong2* pB = hp + (size_t)J * 2048 + (size_t)lq * 128 + wc * 64 + lr;

    f32x4 acc[4][4];
    #pragma unroll
    for (int m = 0; m < 4; ++m)
        #pragma unroll
        for (int n = 0; n < 4; ++n) acc[m][n] = (f32x4){0.f, 0.f, 0.f, 0.f};

    // All 32 fragment loads upfront: 32 outstanding L2 reads per lane.
    ulonglong2 fA[4][4], fB[4][4];
    #pragma unroll
    for (int tt = 0; tt < 4; ++tt) {
        #pragma unroll
        for (int m = 0; m < 4; ++m) fA[tt][m] = pA[tt * 512 + m * 16];
        #pragma unroll
        for (int n = 0; n < 4; ++n) fB[tt][n] = pB[tt * 512 + n * 16];
    }

    #pragma unroll
    for (int tt = 0; tt < 4; ++tt) {
        // k-block 2t: first octet (.x) of each 16B unit
        #pragma unroll
        for (int m = 0; m < 4; ++m)
            #pragma unroll
            for (int n = 0; n < 4; ++n)
                acc[m][n] = __builtin_amdgcn_mfma_f32_16x16x32_fp8_fp8(
                    (long)fA[tt][m].x, (long)fB[tt][n].x, acc[m][n], 0, 0, 0);
        // k-block 2t+1: second octet (.y)
        #pragma unroll
        for (int m = 0; m < 4; ++m)
            #pragma unroll
            for (int n = 0; n < 4; ++n)
                acc[m][n] = __builtin_amdgcn_mfma_f32_16x16x32_fp8_fp8(
                    (long)fA[tt][m].y, (long)fB[tt][n].y, acc[m][n], 0, 0, 0);
    }

    // ---- epilogue: L2 -> sum of 5 Gaussian kernels -> reduce (frozen math)
    float scale = *scale_p;
    int ro_eff = I * 128 + wr * 64;
    int co_eff = J * 128 + wc * 64;
    float4 sqa4[4];
    float  sqbv[4];
    #pragma unroll
    for (int m = 0; m < 4; ++m) sqa4[m] = *(const float4*)&sq[ro_eff + m * 16 + lq * 4];
    #pragma unroll
    for (int n = 0; n < 4; ++n) sqbv[n] = sq[co_eff + n * 16 + lr];

    float tsum = 0.0f;
    #pragma unroll
    for (int m = 0; m < 4; ++m) {
        float sa[4] = {sqa4[m].x, sqa4[m].y, sqa4[m].z, sqa4[m].w};
        #pragma unroll
        for (int n = 0; n < 4; ++n) {
            #pragma unroll
            for (int r = 0; r < 4; ++r) {
                float L2  = sa[r] + sqbv[n] - 2.0f * acc[m][n][r];
                float u   = __builtin_amdgcn_exp2f(scale * L2);
                float u2  = u * u;
                float u4  = u2 * u2;
                float u8  = u4 * u4;
                float u16 = u8 * u8;
                tsum += u + u2 + u4 + u8 + u16;     // 5 kernel scales
            }
        }
    }

    #pragma unroll
    for (int off = 32; off; off >>= 1) tsum += __shfl_xor(tsum, off, 64);
    if (lane == 0) wsum[w] = tsum;
    __syncthreads();
    if (t == 0) {
        float tot = wsum[0] + wsum[1] + wsum[2] + wsum[3];
        // pre-normalized float atomic straight into d_out (R13-verified)
        atomicAdd(out, tot * sgn * wgt * (1.0f / ((float)HALF * (float)HALF)));
    }
}

extern "C" void kernel_launch(void* const* d_in, const int* in_sizes, int n_in,
                              void* d_out, int out_size, void* d_ws, size_t ws_size,
                              hipStream_t stream) {
    const float* src = (const float*)d_in[0];
    const float* tgt = (const float*)d_in[1];
    float* out = (float*)d_out;

    char* ws = (char*)d_ws;
    float*  scale  = (float*)(ws + 16);                          // 4 B
    float*  sq     = (float*)(ws + 64);                          // 32768 B
    float*  part   = (float*)(ws + 64 + 32768);                  // 256*256*4 B
    double* parts1 = (double*)(ws + 64 + 32768 + 262144);        // 256*8 B
    unsigned char* hi = (unsigned char*)(ws + 297024);           // 2 MB, 16B-aligned

    k_conv <<<CONVB, 256, 0, stream>>>(src, tgt, hi, sq, part, parts1, out);
    k_scale<<<1, 256, 0, stream>>>(parts1, part, scale);
    k_pairs<<<NTILE, 256, 0, stream>>>(hi, sq, scale, out);
}

// Round 4
// 103.437 us; speedup vs baseline: 1.7579x; 1.0111x over previous
//
#include <hip/hip_runtime.h>

// MMD loss, N=4096 per side, D=256, fp32.
// R20: LDS-staged fp8 k_pairs (m97 structure). Evidence trail: R18 (2.2x
//      occupancy, dbuf) ~no gain; R19 (fp8: VMEM bytes+instr halved) small
//      gain; L2-hot replay = same dur. -> binder is burst-then-stall phase
//      serialization: every wave stalls at vmcnt(0) for its whole fragment
//      burst, CU alternates {L2 stream, MFMA idle}/{MFMA, VMEM idle}.
//      Fix = global_load_lds DMA staging (no VGPR round-trip, no register-
//      dependence stall; co-resident block overlaps) + kills the 2x intra-
//      block wave duplication (panels staged once per block).
//      - LDS: panel I + panel J fp8 planes, 32 KB each (64 KB -> 2 blk/CU).
//      - Swizzle: global source row pre-swizzled r ^ ((u&3)<<1); ds_read
//        uses the same XOR -> fragment reads bank-uniform (8 lanes/group,
//        contiguous-equivalent). Both-sides-or-neither (m201 pattern).
//      - Diagonal blocks (J==I) stage one panel, B reads alias A.
//      - Inner loop: 4x {8 ds_read_b128 -> 32 MFMA}; compiler lgkmcnt
//        pipelining (m97-verified) handles the interleave.
//      k_conv/k_scale/plane layout/epilogue math FROZEN from R19.
//      Lessons: NO __threadfence (R8-R10), NO cooperative launch (R17),
//      arrays indexed only by fully-unrolled vars (R8/R9), occupancy is not
//      the lever (R18), VMEM bytes alone not the lever (R19).

#define NROWS 8192
#define HALF  4096
#define DIM   256
#define CONVB 256         // k_conv blocks; 32 rows each (quarter panel)
#define NTILE 2080        // 128x128 tiles: 64*65/2, J>=I

typedef float f32x4 __attribute__((ext_vector_type(4)));

__device__ __forceinline__ const float* row_ptr(const float* src, const float* tgt, int r) {
    return (r < HALF) ? (src + (size_t)r * DIM) : (tgt + (size_t)(r - HALF) * DIM);
}

__device__ __forceinline__ void gload_lds16(const void* g, void* l) {
    __builtin_amdgcn_global_load_lds(
        (const __attribute__((address_space(1))) unsigned int*)g,
        (__attribute__((address_space(3))) unsigned int*)l, 16, 0, 0);
}

// --- Phase 0: fp32 -> fp8 plane (tiled, k-interleaved) + sq/colsum/S1 ---
// Plane unit = 16B of row R: unit u (0..15) = (t=u>>2, j=u&3) holds octets
//   bytes k[64t+8j .. +7]   (-> MFMA k-block 2t,   lane lq=j)
//   bytes k[64t+32+8j .. +7](-> MFMA k-block 2t+1, lane lq=j)
// Unit index of (row R, u) = (R>>7)*2048 + u*128 + (R&127).
__global__ __launch_bounds__(256) void k_conv(const float* __restrict__ src,
                                              const float* __restrict__ tgt,
                                              unsigned char* __restrict__ hi,
                                              float* __restrict__ sq,
                                              float* __restrict__ part,
                                              double* __restrict__ parts1,
                                              float* __restrict__ out) {
    __shared__ __align__(16) unsigned char sh8[32 * 256];  // 8 KB, octet-swizzled
    __shared__ float4 cs[4][64];
    __shared__ double s1s[4];

    int w = threadIdx.x >> 6, lane = threadIdx.x & 63;
    int r0 = blockIdx.x * 32;                       // 32 rows per block

    float4 v[8];
    #pragma unroll
    for (int i = 0; i < 8; ++i) {
        int row = r0 + w * 8 + i;
        v[i] = ((const float4*)row_ptr(src, tgt, row))[lane];   // coalesced
    }

    float4 csum = {0.f, 0.f, 0.f, 0.f};
    double s1w = 0.0;
    #pragma unroll
    for (int i = 0; i < 8; ++i) {
        int rl  = w * 8 + i;                        // local row 0..31
        float xs[4] = {v[i].x, v[i].y, v[i].z, v[i].w};
        int pk = __builtin_amdgcn_cvt_pk_fp8_f32(xs[0], xs[1], 0, false);
        pk     = __builtin_amdgcn_cvt_pk_fp8_f32(xs[2], xs[3], pk, true);
        int o  = lane >> 1, h = lane & 1;           // octet 0..31, 4B half
        *(int*)&sh8[rl * 256 + (((o ^ rl) & 31) << 3) + (h << 2)] = pk;
        csum.x += xs[0]; csum.y += xs[1]; csum.z += xs[2]; csum.w += xs[3];
        float sf = xs[0]*xs[0] + xs[1]*xs[1] + xs[2]*xs[2] + xs[3]*xs[3];
        float q0 = __builtin_amdgcn_cvt_f32_fp8(pk, 0);
        float q1 = __builtin_amdgcn_cvt_f32_fp8(pk, 1);
        float q2 = __builtin_amdgcn_cvt_f32_fp8(pk, 2);
        float q3 = __builtin_amdgcn_cvt_f32_fp8(pk, 3);
        float sQ = q0*q0 + q1*q1 + q2*q2 + q3*q3;
        #pragma unroll
        for (int off = 32; off; off >>= 1) {
            sf += __shfl_xor(sf, off, 64);
            sQ += __shfl_xor(sQ, off, 64);
        }
        if (lane == 0) { sq[r0 + rl] = sQ; s1w += (double)sf; }
    }
    __syncthreads();
    // Coalesced tiled write-out: 512 units of 16 B (k-interleaved pairing).
    int panel = blockIdx.x >> 2, quarter = blockIdx.x & 3;
    #pragma unroll
    for (int c = threadIdx.x; c < 512; c += 256) {
        int u = c >> 5, rl = c & 31;
        int tt = u >> 2, j = u & 3;
        int o0 = 8 * tt + j;                        // k[64t+8j]
        int o1 = 8 * tt + 4 + j;                    // k[64t+32+8j]
        unsigned long long q0 = *(const unsigned long long*)
            &sh8[rl * 256 + (((o0 ^ rl) & 31) << 3)];
        unsigned long long q1 = *(const unsigned long long*)
            &sh8[rl * 256 + (((o1 ^ rl) & 31) << 3)];
        ulonglong2 q = {q0, q1};
        size_t goff = ((size_t)panel * 2048 + (size_t)u * 128 + quarter * 32 + rl);
        ((ulonglong2*)hi)[goff] = q;
    }
    cs[w][lane] = csum;
    if (lane == 0) s1s[w] = s1w;
    __syncthreads();
    if (w == 0) {
        float4 a = cs[0][lane], b = cs[1][lane], c = cs[2][lane], d = cs[3][lane];
        float4 tot = {a.x + b.x + c.x + d.x, a.y + b.y + c.y + d.y,
                      a.z + b.z + c.z + d.z, a.w + b.w + c.w + d.w};
        *(float4*)&part[(size_t)blockIdx.x * DIM + lane * 4] = tot;
        if (lane == 0) parts1[blockIdx.x] = s1s[0] + s1s[1] + s1s[2] + s1s[3];
    }
    if (blockIdx.x == 0 && threadIdx.x == 0) out[0] = 0.0f;  // d_out was 0xAA
}

// --- Phase 1: bandwidth -> exp2 scale factor (unchanged, fp32 stats) ---
__global__ __launch_bounds__(256) void k_scale(const double* __restrict__ parts1,
                                               const float* __restrict__ part,
                                               float* __restrict__ scale) {
    __shared__ double sh[256];
    int t = threadIdx.x;
    sh[t] = parts1[t];
    __syncthreads();
    for (int off = 128; off; off >>= 1) {
        if (t < off) sh[t] += sh[t + off];
        __syncthreads();
    }
    double S1 = sh[0];
    __syncthreads();
    float c0 = 0.f, c1 = 0.f, c2 = 0.f, c3 = 0.f;
    #pragma unroll 16
    for (int b = 0; b < CONVB; b += 4) {
        c0 += part[(b + 0) * DIM + t];
        c1 += part[(b + 1) * DIM + t];
        c2 += part[(b + 2) * DIM + t];
        c3 += part[(b + 3) * DIM + t];
    }
    double c = (double)((c0 + c1) + (c2 + c3));
    sh[t] = c * c;
    __syncthreads();
    for (int off = 128; off; off >>= 1) {
        if (t < off) sh[t] += sh[t + off];
        __syncthreads();
    }
    if (t == 0) {
        double S2    = sh[0];
        double n     = (double)NROWS;
        double sumL2 = 2.0 * n * S1 - 2.0 * S2;
        double bw    = sumL2 / (n * n - n) / 4.0;   // / KERNEL_MUL^(KERNEL_NUM//2)
        *scale = (float)(-1.0 / (16.0 * bw * 0.69314718055994530942));
    }
}

// --- Phase 2: LDS-staged fp8 MFMA pair kernel, 128x128 tile, J>=I ---
// Panels DMA'd to LDS via global_load_lds(16B) with source-side row swizzle
// r ^ ((u&3)<<1); ds_read_b128 fragment reads use the same XOR -> bank-
// uniform (8 lanes per 4-bank group = contiguous-equivalent).
__global__ __launch_bounds__(256, 2) void k_pairs(const unsigned char* __restrict__ hi,
                                                  const float* __restrict__ sq,
                                                  const float* __restrict__ scale_p,
                                                  float* __restrict__ out) {
    __shared__ __align__(16) ulonglong2 ldsA[2048];   // 32 KB: panel I
    __shared__ __align__(16) ulonglong2 ldsB[2048];   // 32 KB: panel J
    __shared__ float wsum[4];

    // Triangular decode: row panel I (128 rows), col panel J = I..63.
    int id = blockIdx.x;
    int I = 0;
    for (;;) {
        int cnt = 64 - I;
        if (id < cnt) break;
        id -= cnt; ++I;
    }
    int J = I + id;

    int t    = threadIdx.x;
    int lane = t & 63;
    int w    = t >> 6;
    int lr   = lane & 15, lq = lane >> 4;
    int wr   = w >> 1, wc = w & 1;                  // 2x2 wave grid of 64x64

    float wgt = (J == I) ? 1.0f : 2.0f;
    float sgn = ((I < 32) == (J < 32)) ? 1.0f : -1.0f;

    // ---- DMA staging: 64 wave-instrs (32 if diagonal), wave w takes k%4==w.
    // instr k: panel p=k>>5, unit u=(k>>1)&15, half h=k&1, rows rs=h*64+lane.
    // Source row pre-swizzled: rg = rs ^ ((u&3)<<1); LDS stays linear.
    const ulonglong2* plane = (const ulonglong2*)hi;
    int nIns = (J == I) ? 32 : 64;
    for (int i = 0; i < 16; ++i) {
        int k = w + 4 * i;
        if (k >= nIns) break;                        // wave-uniform
        int p  = k >> 5;
        int u  = (k >> 1) & 15;
        int h  = k & 1;
        int rg = (h * 64 + lane) ^ ((u & 3) << 1);
        size_t gUnit = (size_t)(p ? J : I) * 2048 + (size_t)u * 128 + rg;
        ulonglong2* ldst = (p ? ldsB : ldsA) + (u * 128 + h * 64);  // uniform base
        gload_lds16(plane + gUnit, ldst);
    }
    asm volatile("s_waitcnt vmcnt(0)");
    __syncthreads();

    const ulonglong2* lA = ldsA;
    const ulonglong2* lB = (J == I) ? ldsA : ldsB;
    // Lane fragment base: unit lq, swizzled row. XOR only touches bits[2:1]
    // of lr (lq<8), so (R ^ (lq<<1)) == wr*64 + m*16 + (lr ^ (lq<<1)).
    int lrx = lr ^ (lq << 1);
    const ulonglong2* pAl = lA + lq * 128 + wr * 64 + lrx;
    const ulonglong2* pBl = lB + lq * 128 + wc * 64 + lrx;

    f32x4 acc[4][4];
    #pragma unroll
    for (int m = 0; m < 4; ++m)
        #pragma unroll
        for (int n = 0; n < 4; ++n) acc[m][n] = (f32x4){0.f, 0.f, 0.f, 0.f};

    #pragma unroll
    for (int tt = 0; tt < 4; ++tt) {
        ulonglong2 fA[4], fB[4];
        #pragma unroll
        for (int m = 0; m < 4; ++m) fA[m] = pAl[tt * 512 + m * 16];
        #pragma unroll
        for (int n = 0; n < 4; ++n) fB[n] = pBl[tt * 512 + n * 16];
        // k-block 2t: first octet (.x); k-block 2t+1: second octet (.y)
        #pragma unroll
        for (int m = 0; m < 4; ++m)
            #pragma unroll
            for (int n = 0; n < 4; ++n)
                acc[m][n] = __builtin_amdgcn_mfma_f32_16x16x32_fp8_fp8(
                    (long)fA[m].x, (long)fB[n].x, acc[m][n], 0, 0, 0);
        #pragma unroll
        for (int m = 0; m < 4; ++m)
            #pragma unroll
            for (int n = 0; n < 4; ++n)
                acc[m][n] = __builtin_amdgcn_mfma_f32_16x16x32_fp8_fp8(
                    (long)fA[m].y, (long)fB[n].y, acc[m][n], 0, 0, 0);
    }

    // ---- epilogue: L2 -> sum of 5 Gaussian kernels -> reduce (frozen math)
    float scale = *scale_p;
    int ro_eff = I * 128 + wr * 64;
    int co_eff = J * 128 + wc * 64;
    float4 sqa4[4];
    float  sqbv[4];
    #pragma unroll
    for (int m = 0; m < 4; ++m) sqa4[m] = *(const float4*)&sq[ro_eff + m * 16 + lq * 4];
    #pragma unroll
    for (int n = 0; n < 4; ++n) sqbv[n] = sq[co_eff + n * 16 + lr];

    float tsum = 0.0f;
    #pragma unroll
    for (int m = 0; m < 4; ++m) {
        float sa[4] = {sqa4[m].x, sqa4[m].y, sqa4[m].z, sqa4[m].w};
        #pragma unroll
        for (int n = 0; n < 4; ++n) {
            #pragma unroll
            for (int r = 0; r < 4; ++r) {
                float L2  = sa[r] + sqbv[n] - 2.0f * acc[m][n][r];
                float u   = __builtin_amdgcn_exp2f(scale * L2);
                float u2  = u * u;
                float u4  = u2 * u2;
                float u8  = u4 * u4;
                float u16 = u8 * u8;
                tsum += u + u2 + u4 + u8 + u16;     // 5 kernel scales
            }
        }
    }

    #pragma unroll
    for (int off = 32; off; off >>= 1) tsum += __shfl_xor(tsum, off, 64);
    if (lane == 0) wsum[w] = tsum;
    __syncthreads();
    if (t == 0) {
        float tot = wsum[0] + wsum[1] + wsum[2] + wsum[3];
        // pre-normalized float atomic straight into d_out (R13-verified)
        atomicAdd(out, tot * sgn * wgt * (1.0f / ((float)HALF * (float)HALF)));
    }
}

extern "C" void kernel_launch(void* const* d_in, const int* in_sizes, int n_in,
                              void* d_out, int out_size, void* d_ws, size_t ws_size,
                              hipStream_t stream) {
    const float* src = (const float*)d_in[0];
    const float* tgt = (const float*)d_in[1];
    float* out = (float*)d_out;

    char* ws = (char*)d_ws;
    float*  scale  = (float*)(ws + 16);                          // 4 B
    float*  sq     = (float*)(ws + 64);                          // 32768 B
    float*  part   = (float*)(ws + 64 + 32768);                  // 256*256*4 B
    double* parts1 = (double*)(ws + 64 + 32768 + 262144);        // 256*8 B
    unsigned char* hi = (unsigned char*)(ws + 297024);           // 2 MB, 16B-aligned

    k_conv <<<CONVB, 256, 0, stream>>>(src, tgt, hi, sq, part, parts1, out);
    k_scale<<<1, 256, 0, stream>>>(parts1, part, scale);
    k_pairs<<<NTILE, 256, 0, stream>>>(hi, sq, scale, out);
}

// Round 5
// 101.260 us; speedup vs baseline: 1.7957x; 1.0215x over previous
//
#include <hip/hip_runtime.h>

// MMD loss, N=4096 per side, D=256, fp32.
// R21: kill the same-address atomic stream. Evidence: 4 data-path rewrites
//      (R18 occupancy 2.2x, R19 fp8 2x bytes+instr, R20 LDS-DMA) each moved
//      k_pairs <=10% -> delivery is not the binder. Bottom-up, a block does
//      ~1.3 us work but wall-time is ~11 us/block with all pipes <30% and
//      occupancy 29% (wave-0s resident-idle). Unique fit: 2080 blocks all
//      atomicAdd the SAME d_out address; cross-XCD same-address atomics
//      serialize at the device coherent point (~20 ns each ~= 42 us) and
//      each block's wave 0 waits vmcnt(0) on its ack -> makespan floor.
//      Explains: R18 49us ~= floor+ramp; R16 (1056 atomics, 21us floor)
//      hidden under 45us compute = the R15 "plateau"; L2-hot replay
//      identical; nothing-busy stall. Also note: the 41.6us 268MB workspace
//      re-poison fill is stream-ordered INSIDE the timed region = the true
//      "fixed residue" (untouchable).
//      Fix: per-block plain STORE into pb[blockIdx.x] (no contention, no
//      ack queue) + tiny k_fin reduces 2080 floats -> out (stream-ordered,
//      coherence via kernel boundary; no atomics anywhere).
//      k_conv / k_scale / k_pairs body+staging byte-frozen from R20.
//      Lessons: NO __threadfence (R8-R10), NO cooperative launch (R17),
//      arrays indexed only by fully-unrolled vars (R8/R9), occupancy not
//      the lever (R18), VMEM bytes not the lever (R19/R20).

#define NROWS 8192
#define HALF  4096
#define DIM   256
#define CONVB 256         // k_conv blocks; 32 rows each (quarter panel)
#define NTILE 2080        // 128x128 tiles: 64*65/2, J>=I

typedef float f32x4 __attribute__((ext_vector_type(4)));

__device__ __forceinline__ const float* row_ptr(const float* src, const float* tgt, int r) {
    return (r < HALF) ? (src + (size_t)r * DIM) : (tgt + (size_t)(r - HALF) * DIM);
}

__device__ __forceinline__ void gload_lds16(const void* g, void* l) {
    __builtin_amdgcn_global_load_lds(
        (const __attribute__((address_space(1))) unsigned int*)g,
        (__attribute__((address_space(3))) unsigned int*)l, 16, 0, 0);
}

// --- Phase 0: fp32 -> fp8 plane (tiled, k-interleaved) + sq/colsum/S1 ---
// Plane unit = 16B of row R: unit u (0..15) = (t=u>>2, j=u&3) holds octets
//   bytes k[64t+8j .. +7]   (-> MFMA k-block 2t,   lane lq=j)
//   bytes k[64t+32+8j .. +7](-> MFMA k-block 2t+1, lane lq=j)
// Unit index of (row R, u) = (R>>7)*2048 + u*128 + (R&127).
__global__ __launch_bounds__(256) void k_conv(const float* __restrict__ src,
                                              const float* __restrict__ tgt,
                                              unsigned char* __restrict__ hi,
                                              float* __restrict__ sq,
                                              float* __restrict__ part,
                                              double* __restrict__ parts1,
                                              float* __restrict__ out) {
    __shared__ __align__(16) unsigned char sh8[32 * 256];  // 8 KB, octet-swizzled
    __shared__ float4 cs[4][64];
    __shared__ double s1s[4];

    int w = threadIdx.x >> 6, lane = threadIdx.x & 63;
    int r0 = blockIdx.x * 32;                       // 32 rows per block

    float4 v[8];
    #pragma unroll
    for (int i = 0; i < 8; ++i) {
        int row = r0 + w * 8 + i;
        v[i] = ((const float4*)row_ptr(src, tgt, row))[lane];   // coalesced
    }

    float4 csum = {0.f, 0.f, 0.f, 0.f};
    double s1w = 0.0;
    #pragma unroll
    for (int i = 0; i < 8; ++i) {
        int rl  = w * 8 + i;                        // local row 0..31
        float xs[4] = {v[i].x, v[i].y, v[i].z, v[i].w};
        int pk = __builtin_amdgcn_cvt_pk_fp8_f32(xs[0], xs[1], 0, false);
        pk     = __builtin_amdgcn_cvt_pk_fp8_f32(xs[2], xs[3], pk, true);
        int o  = lane >> 1, h = lane & 1;           // octet 0..31, 4B half
        *(int*)&sh8[rl * 256 + (((o ^ rl) & 31) << 3) + (h << 2)] = pk;
        csum.x += xs[0]; csum.y += xs[1]; csum.z += xs[2]; csum.w += xs[3];
        float sf = xs[0]*xs[0] + xs[1]*xs[1] + xs[2]*xs[2] + xs[3]*xs[3];
        float q0 = __builtin_amdgcn_cvt_f32_fp8(pk, 0);
        float q1 = __builtin_amdgcn_cvt_f32_fp8(pk, 1);
        float q2 = __builtin_amdgcn_cvt_f32_fp8(pk, 2);
        float q3 = __builtin_amdgcn_cvt_f32_fp8(pk, 3);
        float sQ = q0*q0 + q1*q1 + q2*q2 + q3*q3;
        #pragma unroll
        for (int off = 32; off; off >>= 1) {
            sf += __shfl_xor(sf, off, 64);
            sQ += __shfl_xor(sQ, off, 64);
        }
        if (lane == 0) { sq[r0 + rl] = sQ; s1w += (double)sf; }
    }
    __syncthreads();
    // Coalesced tiled write-out: 512 units of 16 B (k-interleaved pairing).
    int panel = blockIdx.x >> 2, quarter = blockIdx.x & 3;
    #pragma unroll
    for (int c = threadIdx.x; c < 512; c += 256) {
        int u = c >> 5, rl = c & 31;
        int tt = u >> 2, j = u & 3;
        int o0 = 8 * tt + j;                        // k[64t+8j]
        int o1 = 8 * tt + 4 + j;                    // k[64t+32+8j]
        unsigned long long q0 = *(const unsigned long long*)
            &sh8[rl * 256 + (((o0 ^ rl) & 31) << 3)];
        unsigned long long q1 = *(const unsigned long long*)
            &sh8[rl * 256 + (((o1 ^ rl) & 31) << 3)];
        ulonglong2 q = {q0, q1};
        size_t goff = ((size_t)panel * 2048 + (size_t)u * 128 + quarter * 32 + rl);
        ((ulonglong2*)hi)[goff] = q;
    }
    cs[w][lane] = csum;
    if (lane == 0) s1s[w] = s1w;
    __syncthreads();
    if (w == 0) {
        float4 a = cs[0][lane], b = cs[1][lane], c = cs[2][lane], d = cs[3][lane];
        float4 tot = {a.x + b.x + c.x + d.x, a.y + b.y + c.y + d.y,
                      a.z + b.z + c.z + d.z, a.w + b.w + c.w + d.w};
        *(float4*)&part[(size_t)blockIdx.x * DIM + lane * 4] = tot;
        if (lane == 0) parts1[blockIdx.x] = s1s[0] + s1s[1] + s1s[2] + s1s[3];
    }
    if (blockIdx.x == 0 && threadIdx.x == 0) out[0] = 0.0f;  // d_out was 0xAA
}

// --- Phase 1: bandwidth -> exp2 scale factor (unchanged, fp32 stats) ---
__global__ __launch_bounds__(256) void k_scale(const double* __restrict__ parts1,
                                               const float* __restrict__ part,
                                               float* __restrict__ scale) {
    __shared__ double sh[256];
    int t = threadIdx.x;
    sh[t] = parts1[t];
    __syncthreads();
    for (int off = 128; off; off >>= 1) {
        if (t < off) sh[t] += sh[t + off];
        __syncthreads();
    }
    double S1 = sh[0];
    __syncthreads();
    float c0 = 0.f, c1 = 0.f, c2 = 0.f, c3 = 0.f;
    #pragma unroll 16
    for (int b = 0; b < CONVB; b += 4) {
        c0 += part[(b + 0) * DIM + t];
        c1 += part[(b + 1) * DIM + t];
        c2 += part[(b + 2) * DIM + t];
        c3 += part[(b + 3) * DIM + t];
    }
    double c = (double)((c0 + c1) + (c2 + c3));
    sh[t] = c * c;
    __syncthreads();
    for (int off = 128; off; off >>= 1) {
        if (t < off) sh[t] += sh[t + off];
        __syncthreads();
    }
    if (t == 0) {
        double S2    = sh[0];
        double n     = (double)NROWS;
        double sumL2 = 2.0 * n * S1 - 2.0 * S2;
        double bw    = sumL2 / (n * n - n) / 4.0;   // / KERNEL_MUL^(KERNEL_NUM//2)
        *scale = (float)(-1.0 / (16.0 * bw * 0.69314718055994530942));
    }
}

// --- Phase 2: LDS-staged fp8 MFMA pair kernel, 128x128 tile, J>=I ---
// Per-block result is a plain contention-free STORE into pb[blockIdx.x]
// (R21: no same-address atomic, no ack queue). k_fin reduces after.
__global__ __launch_bounds__(256, 2) void k_pairs(const unsigned char* __restrict__ hi,
                                                  const float* __restrict__ sq,
                                                  const float* __restrict__ scale_p,
                                                  float* __restrict__ pb) {
    __shared__ __align__(16) ulonglong2 ldsA[2048];   // 32 KB: panel I
    __shared__ __align__(16) ulonglong2 ldsB[2048];   // 32 KB: panel J
    __shared__ float wsum[4];

    // Triangular decode: row panel I (128 rows), col panel J = I..63.
    int id = blockIdx.x;
    int I = 0;
    for (;;) {
        int cnt = 64 - I;
        if (id < cnt) break;
        id -= cnt; ++I;
    }
    int J = I + id;

    int t    = threadIdx.x;
    int lane = t & 63;
    int w    = t >> 6;
    int lr   = lane & 15, lq = lane >> 4;
    int wr   = w >> 1, wc = w & 1;                  // 2x2 wave grid of 64x64

    float wgt = (J == I) ? 1.0f : 2.0f;
    float sgn = ((I < 32) == (J < 32)) ? 1.0f : -1.0f;

    // ---- DMA staging: 64 wave-instrs (32 if diagonal), wave w takes k%4==w.
    const ulonglong2* plane = (const ulonglong2*)hi;
    int nIns = (J == I) ? 32 : 64;
    for (int i = 0; i < 16; ++i) {
        int k = w + 4 * i;
        if (k >= nIns) break;                        // wave-uniform
        int p  = k >> 5;
        int u  = (k >> 1) & 15;
        int h  = k & 1;
        int rg = (h * 64 + lane) ^ ((u & 3) << 1);
        size_t gUnit = (size_t)(p ? J : I) * 2048 + (size_t)u * 128 + rg;
        ulonglong2* ldst = (p ? ldsB : ldsA) + (u * 128 + h * 64);  // uniform base
        gload_lds16(plane + gUnit, ldst);
    }
    asm volatile("s_waitcnt vmcnt(0)");
    __syncthreads();

    const ulonglong2* lA = ldsA;
    const ulonglong2* lB = (J == I) ? ldsA : ldsB;
    int lrx = lr ^ (lq << 1);
    const ulonglong2* pAl = lA + lq * 128 + wr * 64 + lrx;
    const ulonglong2* pBl = lB + lq * 128 + wc * 64 + lrx;

    f32x4 acc[4][4];
    #pragma unroll
    for (int m = 0; m < 4; ++m)
        #pragma unroll
        for (int n = 0; n < 4; ++n) acc[m][n] = (f32x4){0.f, 0.f, 0.f, 0.f};

    #pragma unroll
    for (int tt = 0; tt < 4; ++tt) {
        ulonglong2 fA[4], fB[4];
        #pragma unroll
        for (int m = 0; m < 4; ++m) fA[m] = pAl[tt * 512 + m * 16];
        #pragma unroll
        for (int n = 0; n < 4; ++n) fB[n] = pBl[tt * 512 + n * 16];
        #pragma unroll
        for (int m = 0; m < 4; ++m)
            #pragma unroll
            for (int n = 0; n < 4; ++n)
                acc[m][n] = __builtin_amdgcn_mfma_f32_16x16x32_fp8_fp8(
                    (long)fA[m].x, (long)fB[n].x, acc[m][n], 0, 0, 0);
        #pragma unroll
        for (int m = 0; m < 4; ++m)
            #pragma unroll
            for (int n = 0; n < 4; ++n)
                acc[m][n] = __builtin_amdgcn_mfma_f32_16x16x32_fp8_fp8(
                    (long)fA[m].y, (long)fB[n].y, acc[m][n], 0, 0, 0);
    }

    // ---- epilogue: L2 -> sum of 5 Gaussian kernels -> reduce (frozen math)
    float scale = *scale_p;
    int ro_eff = I * 128 + wr * 64;
    int co_eff = J * 128 + wc * 64;
    float4 sqa4[4];
    float  sqbv[4];
    #pragma unroll
    for (int m = 0; m < 4; ++m) sqa4[m] = *(const float4*)&sq[ro_eff + m * 16 + lq * 4];
    #pragma unroll
    for (int n = 0; n < 4; ++n) sqbv[n] = sq[co_eff + n * 16 + lr];

    float tsum = 0.0f;
    #pragma unroll
    for (int m = 0; m < 4; ++m) {
        float sa[4] = {sqa4[m].x, sqa4[m].y, sqa4[m].z, sqa4[m].w};
        #pragma unroll
        for (int n = 0; n < 4; ++n) {
            #pragma unroll
            for (int r = 0; r < 4; ++r) {
                float L2  = sa[r] + sqbv[n] - 2.0f * acc[m][n][r];
                float u   = __builtin_amdgcn_exp2f(scale * L2);
                float u2  = u * u;
                float u4  = u2 * u2;
                float u8  = u4 * u4;
                float u16 = u8 * u8;
                tsum += u + u2 + u4 + u8 + u16;     // 5 kernel scales
            }
        }
    }

    #pragma unroll
    for (int off = 32; off; off >>= 1) tsum += __shfl_xor(tsum, off, 64);
    if (lane == 0) wsum[w] = tsum;
    __syncthreads();
    if (t == 0) {
        float tot = wsum[0] + wsum[1] + wsum[2] + wsum[3];
        // R21: plain per-block store (no contention, no coherent-point queue)
        pb[blockIdx.x] = tot * sgn * wgt * (1.0f / ((float)HALF * (float)HALF));
    }
}

// --- Phase 3: reduce 2080 per-block partials -> out (single small block) ---
__global__ __launch_bounds__(256) void k_fin(const float* __restrict__ pb,
                                             float* __restrict__ out) {
    __shared__ float sh[4];
    int t = threadIdx.x, lane = t & 63, w = t >> 6;
    float s = 0.f;
    for (int i = t; i < NTILE; i += 256) s += pb[i];
    #pragma unroll
    for (int off = 32; off; off >>= 1) s += __shfl_xor(s, off, 64);
    if (lane == 0) sh[w] = s;
    __syncthreads();
    if (t == 0) out[0] = sh[0] + sh[1] + sh[2] + sh[3];
}

extern "C" void kernel_launch(void* const* d_in, const int* in_sizes, int n_in,
                              void* d_out, int out_size, void* d_ws, size_t ws_size,
                              hipStream_t stream) {
    const float* src = (const float*)d_in[0];
    const float* tgt = (const float*)d_in[1];
    float* out = (float*)d_out;

    char* ws = (char*)d_ws;
    float*  scale  = (float*)(ws + 16);                          // 4 B
    float*  sq     = (float*)(ws + 64);                          // 32768 B
    float*  part   = (float*)(ws + 64 + 32768);                  // 256*256*4 B
    double* parts1 = (double*)(ws + 64 + 32768 + 262144);        // 256*8 B
    unsigned char* hi = (unsigned char*)(ws + 297024);           // 2 MB, 16B-aligned
    float*  pb     = (float*)(ws + 2394176);                     // 2080*4 B

    k_conv <<<CONVB, 256, 0, stream>>>(src, tgt, hi, sq, part, parts1, out);
    k_scale<<<1, 256, 0, stream>>>(parts1, part, scale);
    k_pairs<<<NTILE, 256, 0, stream>>>(hi, sq, scale, pb);
    k_fin  <<<1, 256, 0, stream>>>(pb, out);
}